// Round 1
// baseline (291.367 us; speedup 1.0000x reference)
//
#include <hip/hip_runtime.h>

// WaveletPatcher: 3-level a-trous db4 SWT (periodic) + overlapping patch extract.
// x: (64, 4096, 32) f32  ->  out: (64*511, 32*4, 16) f32
//   A_{l+1}[t] = sum_j LO[j] * A_l[(t + (4-j)*d) & 4095],  d = 2^l
// c=0:A3, 1:D3, 2:D2, 3:D1.  out[(b*511+p)*2048 + n*64 + c*16 + j], t = 8p+j.
//
// R3 (290us total, kernel ~120us): chunk=64t, 70.7KB LDS -> 2 blocks/CU. Kernel
// phases are barrier-serialized; 8 waves/CU can't overlap the 40us store stream
// with compute. R4: chunk=32t (4 patches), stage c=0 aliased into dead A1 panel:
// 40,576 B LDS -> 4 blocks/CU (16 waves/CU). Costs: input window 96/32 = 3x halo
// refetch (L2 absorbs most: adjacent chunks share 64/96 rows) and +33% halo FMA
// (~3us) -- both small vs store-overlap gain. Nontemporal out stores keep L2 for
// input halos. Stage offsets = 8 mod 32 de-phase store-phase c-groups (4way->2way).

#define NTHREADS 256
#define T_MASK   4095

// float offsets into the shared pool
#define S_IN  100   // IN stride  (covers t rel [-23, 72], idx = trel+23)
#define S_A1  84    // A1 stride  (covers trel [-20, 63], idx = trel+20)
#define S_A2  68    // A2 stride  (covers trel [-12, 55], idx = trel+12)
#define S_ST  44    // stage stride (trel [0, 39])
#define OFF_IN 0
#define OFF_A1 3200                 // 32*100
#define OFF_A2 0                    // aliases IN (x dead after level 1)
#define OFF_ST 5896                 // 3200 + 32*84 + 8 pad (bank de-phase)
#define ST_C   1416                 // 32*44 + 8 (bank de-phase between c)
#define LDS_FLOATS (OFF_ST + 3 * ST_C)   // 10144 floats = 40576 B -> 4 blocks/CU
// stage c=0 (A3) aliases the A1 panel (dead after level 2); c=1..3 live at OFF_ST.

typedef float f4_t __attribute__((ext_vector_type(4)));

__device__ __constant__ float c_lo[8] = {
    -0.010597401784997278f, 0.032883011666982945f, 0.030841381835986965f,
    -0.18703481171888114f, -0.02798376941698385f, 0.6308807679295904f,
    0.7148465705525415f,   0.23037781330885523f};
__device__ __constant__ float c_hi[8] = {
    -0.23037781330885523f, 0.7148465705525415f, -0.6308807679295904f,
    -0.02798376941698385f, 0.18703481171888114f, 0.030841381835986965f,
    -0.032883011666982945f, -0.010597401784997278f};

__global__ __launch_bounds__(NTHREADS, 4) void swt_patch(const float* __restrict__ x,
                                                         float* __restrict__ out) {
    __shared__ float lds[LDS_FLOATS];

    const int blk = blockIdx.x;        // 0..8191
    const int b   = blk >> 7;          // 0..63
    const int cid = blk & 127;         // chunk id
    const int T0  = cid << 5;          // first patch-start t
    const int p0  = cid << 2;          // first patch index (4 per chunk)
    const int tid = threadIdx.x;

    // ---- phase 0: load x[b, T0-23 .. T0+72, all n], transpose into IN[n][trel+23] ----
    // 768 float4 loads (i = t-window index 0..95, n4 = n-quad 0..7): fully coalesced.
    const float* xb = x + (size_t)b * (4096 * 32);
    {
#pragma unroll
        for (int it = 0; it < 3; ++it) {
            const int id = tid + it * NTHREADS;        // 0..767
            const int i  = id >> 3;                    // t-window idx 0..95
            const int n0 = (id & 7) * 4;
            const int t  = (T0 - 23 + i) & T_MASK;
            const float4 v = *(const float4*)&xb[(size_t)t * 32 + n0];
            lds[OFF_IN + (n0 + 0) * S_IN + i] = v.x;
            lds[OFF_IN + (n0 + 1) * S_IN + i] = v.y;
            lds[OFF_IN + (n0 + 2) * S_IN + i] = v.z;
            lds[OFF_IN + (n0 + 3) * S_IN + i] = v.w;
        }
    }
    __syncthreads();

    // ---- level 1 (d=1): IN -> A1 (trel -20..63), D1 -> stage c=3 (trel 0..39) ----
    // quad trel0 = -20+4q, q=0..20; window [trel0-3, trel0+7] = IN idx [4q, 4q+10]
    for (int tsk = tid; tsk < 21 * 32; tsk += NTHREADS) {
        const int n = tsk & 31, q = tsk >> 5;
        const int trel0 = -20 + 4 * q;
        float w[12];
        const int base = OFF_IN + n * S_IN + 4 * q;
        *(float4*)&w[0] = *(const float4*)&lds[base];
        *(float4*)&w[4] = *(const float4*)&lds[base + 4];
        *(float4*)&w[8] = *(const float4*)&lds[base + 8];
        float4 va, vd;
        float* pa = (float*)&va; float* pd = (float*)&vd;
#pragma unroll
        for (int ii = 0; ii < 4; ++ii) {
            float sa = 0.f, sd = 0.f;
#pragma unroll
            for (int j = 0; j < 8; ++j) {              // tap t = trel0+ii+(4-j) -> w[ii+7-j]
                const float v = w[ii + 7 - j];
                sa = fmaf(c_lo[j], v, sa);
                sd = fmaf(c_hi[j], v, sd);
            }
            pa[ii] = sa; pd[ii] = sd;
        }
        *(float4*)&lds[OFF_A1 + n * S_A1 + (trel0 + 20)] = va;
        if (trel0 >= 0 && trel0 <= 36)
            *(float4*)&lds[OFF_ST + 2 * ST_C + n * S_ST + trel0] = vd;
    }
    __syncthreads();

    // ---- level 2 (d=2): A1 -> A2 (trel -12..55, overwrites IN), D2 -> stage c=2 ----
    // quad trel0 = -12+4q, q=0..16; window [trel0-6, trel0+11] subset of A1 idx [4q, 4q+19]
    for (int tsk = tid; tsk < 17 * 32; tsk += NTHREADS) {
        const int n = tsk & 31, q = tsk >> 5;
        const int trel0 = -12 + 4 * q;
        float w[20];
        const int base = OFF_A1 + n * S_A1 + 4 * q;    // A1 idx 4q <-> trel trel0-8
#pragma unroll
        for (int c4 = 0; c4 < 5; ++c4)
            *(float4*)&w[4 * c4] = *(const float4*)&lds[base + 4 * c4];
        float4 va, vd;
        float* pa = (float*)&va; float* pd = (float*)&vd;
#pragma unroll
        for (int ii = 0; ii < 4; ++ii) {
            float sa = 0.f, sd = 0.f;
#pragma unroll
            for (int j = 0; j < 8; ++j) {              // tap trel0+ii+2(4-j) -> w[ii+16-2j]
                const float v = w[ii + 16 - 2 * j];
                sa = fmaf(c_lo[j], v, sa);
                sd = fmaf(c_hi[j], v, sd);
            }
            pa[ii] = sa; pd[ii] = sd;
        }
        *(float4*)&lds[OFF_A2 + n * S_A2 + (trel0 + 12)] = va;
        if (trel0 >= 0 && trel0 <= 36)
            *(float4*)&lds[OFF_ST + 1 * ST_C + n * S_ST + trel0] = vd;
    }
    __syncthreads();

    // ---- level 3 (d=4): A2 -> A3 (stage c=0, aliases A1), D3 (stage c=1), trel 0..39 ----
    // quad trel0 = 4q, q=0..9; window [trel0-12, trel0+19] = A2 idx [trel0, trel0+31]
    for (int tsk = tid; tsk < 10 * 32; tsk += NTHREADS) {
        const int n = tsk & 31, q = tsk >> 5;
        const int trel0 = 4 * q;
        float w[32];
        const int base = OFF_A2 + n * S_A2 + trel0;    // A2 idx trel0 <-> trel trel0-12
#pragma unroll
        for (int c4 = 0; c4 < 8; ++c4)
            *(float4*)&w[4 * c4] = *(const float4*)&lds[base + 4 * c4];
        float4 va, vd;
        float* pa = (float*)&va; float* pd = (float*)&vd;
#pragma unroll
        for (int ii = 0; ii < 4; ++ii) {
            float sa = 0.f, sd = 0.f;
#pragma unroll
            for (int j = 0; j < 8; ++j) {              // tap trel0+ii+4(4-j) -> w[ii+28-4j]
                const float v = w[ii + 28 - 4 * j];
                sa = fmaf(c_lo[j], v, sa);
                sd = fmaf(c_hi[j], v, sd);
            }
            pa[ii] = sa; pd[ii] = sd;
        }
        *(float4*)&lds[OFF_A1 + n * S_ST + trel0] = va;            // c=0 in dead A1 panel
        *(float4*)&lds[OFF_ST + 0 * ST_C + n * S_ST + trel0] = vd; // c=1
    }
    __syncthreads();

    // ---- store: 4 patches = ONE contiguous 32KB region, nontemporal float4 streaming ----
    // region float4 idx e4: p_local = e4>>9, n = (e4>>4)&31, c = (e4>>2)&3, jq = e4&3
    f4_t* out4 = (f4_t*)(out + ((size_t)b * 511 + p0) * 2048);
#pragma unroll
    for (int it = 0; it < 8; ++it) {
        const int e4 = tid + it * NTHREADS;            // 0..2047
        const int p_local = e4 >> 9;
        if (p0 + p_local < 511) {
            const int n  = (e4 >> 4) & 31;
            const int c  = (e4 >> 2) & 3;
            const int trel = 8 * p_local + 4 * (e4 & 3);
            const int cb = (c == 0) ? OFF_A1 : (OFF_ST + (c - 1) * ST_C);
            const f4_t v = *(const f4_t*)&lds[cb + n * S_ST + trel];
            __builtin_nontemporal_store(v, &out4[e4]);
        }
    }
}

extern "C" void kernel_launch(void* const* d_in, const int* in_sizes, int n_in,
                              void* d_out, int out_size, void* d_ws, size_t ws_size,
                              hipStream_t stream) {
    const float* x = (const float*)d_in[0];
    float* out = (float*)d_out;
    hipLaunchKernelGGL(swt_patch, dim3(64 * 128), dim3(NTHREADS), 0, stream, x, out);
}